// Round 3
// baseline (326.984 us; speedup 1.0000x reference)
//
#include <hip/hip_runtime.h>
#include <hip/hip_bf16.h>

#define HIST 50
#define N_ITEMS 100000
#define N_USERS 16384

typedef __bf16 bf8 __attribute__((ext_vector_type(8)));
typedef float  f4  __attribute__((ext_vector_type(4)));
typedef float  f4v __attribute__((ext_vector_type(4)));

__device__ __forceinline__ unsigned short f2bf(float x) {
    unsigned u = __builtin_bit_cast(unsigned, x);
    u += 0x7fffu + ((u >> 16) & 1u);          // RNE
    return (unsigned short)(u >> 16);
}
__device__ __forceinline__ float bf2f(unsigned b) {
    unsigned u = b << 16;
    return __builtin_bit_cast(float, u);
}

// ---------------------------------------------------------------------------
// Weight packer: fp32 [K][N] -> bf16 MFMA B-fragments. (verified r2-r4)
// Frag unit (nt, ks, lane l): 8 bf16 = B[ks*32 + (l>>4)*8 + j][nt*16 + (l&15)]
// stored at frag index (nt*KS + ks)*64 + l (16 B per lane).
// ---------------------------------------------------------------------------
__global__ void pack_weights(const float* __restrict__ W1i, const float* __restrict__ W2i,
                             const float* __restrict__ W1u, const float* __restrict__ W2u,
                             unsigned short* __restrict__ dstbase)
{
    int i = blockIdx.x * 256 + threadIdx.x;   // 57344 total
    const float* W; unsigned short* dst; int N, KS, loc;
    if (i < 24576)      { W = W1i; dst = dstbase;          N = 512; KS = 12; loc = i; }
    else if (i < 32768) { W = W2i; dst = dstbase + 196608; N = 128; KS = 16; loc = i - 24576; }
    else if (i < 49152) { W = W1u; dst = dstbase + 262144; N = 512; KS = 8;  loc = i - 32768; }
    else                { W = W2u; dst = dstbase + 393216; N = 128; KS = 16; loc = i - 49152; }
    int l = loc & 63, fi = loc >> 6;
    int ks = fi % KS, nt = fi / KS;
    int q = l >> 4, c = l & 15;
    const float* src = W + (size_t)(ks * 32 + q * 8) * N + nt * 16 + c;
    unsigned o[4];
    #pragma unroll
    for (int k = 0; k < 4; ++k) {
        unsigned lo = f2bf(src[(2 * k) * N]);
        unsigned hi = f2bf(src[(2 * k + 1) * N]);
        o[k] = lo | (hi << 16);
    }
    uint4 v; v.x = o[0]; v.y = o[1]; v.z = o[2]; v.w = o[3];
    ((uint4*)dst)[(size_t)(nt * KS + ks) * 64 + l] = v;
}

// ---------------------------------------------------------------------------
// Core: NR*16 rows, 8 waves (512 thr). Weight (b-frag) loads are the latency
// bottleneck (L2-resident if streams use nt loads): explicit ks+1 prefetch
// gives 4-deep MLP. acc in AGPR (NR=4: 64) + ~64 arch VGPR -> 4 waves/SIMD.
// Layer1: wave w owns cols [w*64, w*64+64) (4 nt); acc1[NR][4].
// Layer2: rg=w>>2 row half, jj=w&3 col quarter; acc2[NR/2][2].
// MFMA 16x16x32 bf16: A-frag m=l&15,k=q*8+j; B n=l&15,k same; D row=q*4+reg,
// col=l&15 (m89-verified).
// ---------------------------------------------------------------------------
template<int NR, int KS1, int ASTR, bool OUT_BF16>
__device__ __forceinline__ void tower_core(
    unsigned short* U, const float* b1s, const float* b2s, float* sumsq,
    const bf8* __restrict__ w1f, const bf8* __restrict__ w2f,
    void* __restrict__ outp, int row0, int nval, int tid)
{
    const int HSTR = 520;                     // 1040 B = 65*16: even bank spread
    const int l = tid & 63, w = tid >> 6;     // w in 0..7
    const int q = l >> 4, c = l & 15;

    f4 acc1[NR][4];
    #pragma unroll
    for (int i = 0; i < NR; ++i)
        #pragma unroll
        for (int j = 0; j < 4; ++j) acc1[i][j] = (f4)0.0f;

    const unsigned short* ap = U + c * ASTR + q * 8;
    bf8 bcur[4], bnxt[4];
    #pragma unroll
    for (int nt = 0; nt < 4; ++nt)
        bcur[nt] = w1f[(size_t)((w * 4 + nt) * KS1 + 0) * 64 + l];
    #pragma unroll
    for (int ks = 0; ks < KS1; ++ks) {
        if (ks + 1 < KS1) {
            #pragma unroll
            for (int nt = 0; nt < 4; ++nt)
                bnxt[nt] = w1f[(size_t)((w * 4 + nt) * KS1 + ks + 1) * 64 + l];
        }
        bf8 a[NR];
        #pragma unroll
        for (int rt = 0; rt < NR; ++rt)
            a[rt] = *(const bf8*)(ap + rt * 16 * ASTR + ks * 32);
        #pragma unroll
        for (int rt = 0; rt < NR; ++rt)
            #pragma unroll
            for (int nt = 0; nt < 4; ++nt)
                acc1[rt][nt] = __builtin_amdgcn_mfma_f32_16x16x32_bf16(a[rt], bcur[nt], acc1[rt][nt], 0, 0, 0);
        #pragma unroll
        for (int nt = 0; nt < 4; ++nt) bcur[nt] = bnxt[nt];
    }
    __syncthreads();                          // all A reads done; U becomes H

    #pragma unroll
    for (int nt = 0; nt < 4; ++nt) {
        int col = w * 64 + nt * 16 + c;
        float bias = b1s[col];
        #pragma unroll
        for (int rt = 0; rt < NR; ++rt)
            #pragma unroll
            for (int reg = 0; reg < 4; ++reg) {
                float h = fmaxf(acc1[rt][nt][reg] + bias, 0.0f);
                U[(rt * 16 + q * 4 + reg) * HSTR + col] = f2bf(h);
            }
    }
    __syncthreads();

    // layer 2: K=512 (16 k-steps); wave w: rows rg*(NR2*16)..+, cols jj*32..+31
    constexpr int NR2 = NR / 2;
    const int rg = w >> 2, jj = w & 3;
    f4 acc2[NR2][2];
    #pragma unroll
    for (int i = 0; i < NR2; ++i) { acc2[i][0] = (f4)0.0f; acc2[i][1] = (f4)0.0f; }

    const unsigned short* hp = U + (size_t)(rg * NR2 * 16 + c) * HSTR + q * 8;
    bf8 ccur[2], cnxt[2];
    ccur[0] = w2f[(size_t)((jj * 2 + 0) * 16 + 0) * 64 + l];
    ccur[1] = w2f[(size_t)((jj * 2 + 1) * 16 + 0) * 64 + l];
    #pragma unroll
    for (int ks = 0; ks < 16; ++ks) {
        if (ks + 1 < 16) {
            cnxt[0] = w2f[(size_t)((jj * 2 + 0) * 16 + ks + 1) * 64 + l];
            cnxt[1] = w2f[(size_t)((jj * 2 + 1) * 16 + ks + 1) * 64 + l];
        }
        bf8 a[NR2];
        #pragma unroll
        for (int i = 0; i < NR2; ++i)
            a[i] = *(const bf8*)(hp + i * 16 * HSTR + ks * 32);
        #pragma unroll
        for (int i = 0; i < NR2; ++i) {
            acc2[i][0] = __builtin_amdgcn_mfma_f32_16x16x32_bf16(a[i], ccur[0], acc2[i][0], 0, 0, 0);
            acc2[i][1] = __builtin_amdgcn_mfma_f32_16x16x32_bf16(a[i], ccur[1], acc2[i][1], 0, 0, 0);
        }
        ccur[0] = cnxt[0]; ccur[1] = cnxt[1];
    }

    // epilogue: +b2, l2norm (16-lane shfl + LDS atomic across jj-waves), store
    float v[NR2][2][4];
    #pragma unroll
    for (int i = 0; i < NR2; ++i)
        #pragma unroll
        for (int j = 0; j < 2; ++j) {
            float bias = b2s[jj * 32 + j * 16 + c];
            #pragma unroll
            for (int reg = 0; reg < 4; ++reg)
                v[i][j][reg] = acc2[i][j][reg] + bias;
        }
    #pragma unroll
    for (int i = 0; i < NR2; ++i)
        #pragma unroll
        for (int reg = 0; reg < 4; ++reg) {
            float s = v[i][0][reg] * v[i][0][reg] + v[i][1][reg] * v[i][1][reg];
            s += __shfl_xor(s, 1); s += __shfl_xor(s, 2);
            s += __shfl_xor(s, 4); s += __shfl_xor(s, 8);
            if (c == 0) atomicAdd(&sumsq[rg * NR2 * 16 + i * 16 + q * 4 + reg], s);
        }
    __syncthreads();
    #pragma unroll
    for (int i = 0; i < NR2; ++i)
        #pragma unroll
        for (int reg = 0; reg < 4; ++reg) {
            int row = rg * NR2 * 16 + i * 16 + q * 4 + reg;
            if (row < nval) {
                float inv = 1.0f / fmaxf(sqrtf(sumsq[row]), 1e-12f);
                #pragma unroll
                for (int j = 0; j < 2; ++j) {
                    int col = jj * 32 + j * 16 + c;
                    float o = v[i][j][reg] * inv;
                    if (OUT_BF16)
                        __builtin_nontemporal_store(f2bf(o),
                            ((unsigned short*)outp) + (size_t)(row0 + row) * 128 + col);
                    else
                        __builtin_nontemporal_store(o,
                            ((float*)outp) + (size_t)(row0 + row) * 128 + col);
                }
            }
        }
}

#define ASI 392   // item A stride (384+8): 784 B = 49*16 -> even bank spread
#define ASU 264   // user A stride (256+8): 528 B = 33*16

__global__ __launch_bounds__(512, 4) void item_kernel(
    const float* __restrict__ text, const float* __restrict__ gcn,
    const bf8* __restrict__ w1f, const float* __restrict__ b1,
    const bf8* __restrict__ w2f, const float* __restrict__ b2,
    unsigned short* __restrict__ item_bf)
{
    __shared__ __align__(16) unsigned short U[64 * 520];   // 66.6 KB union A/H
    __shared__ float b1s[512], b2s[128], sumsq[64];
    const int tid = threadIdx.x;
    const int row0 = blockIdx.x * 64;
    const int nval = min(64, N_ITEMS - row0);
    const f4v* t4 = (const f4v*)text;
    const f4v* g4 = (const f4v*)gcn;
    #pragma unroll
    for (int j = 0; j < 8; ++j) {             // text: 64 x 256 (4096 float4), nt stream
        int idx = tid + j * 512; int r = idx >> 6, c4 = idx & 63;
        f4v x = (r < nval) ? __builtin_nontemporal_load(t4 + (size_t)(row0 + r) * 64 + c4)
                           : (f4v)0.0f;
        ushort4 s; s.x = f2bf(x[0]); s.y = f2bf(x[1]); s.z = f2bf(x[2]); s.w = f2bf(x[3]);
        *(ushort4*)(U + r * ASI + c4 * 4) = s;
    }
    #pragma unroll
    for (int j = 0; j < 4; ++j) {             // gcn: 64 x 128 (2048 float4), nt stream
        int idx = tid + j * 512; int r = idx >> 5, c4 = idx & 31;
        f4v x = (r < nval) ? __builtin_nontemporal_load(g4 + (size_t)(row0 + r) * 32 + c4)
                           : (f4v)0.0f;
        ushort4 s; s.x = f2bf(x[0]); s.y = f2bf(x[1]); s.z = f2bf(x[2]); s.w = f2bf(x[3]);
        *(ushort4*)(U + r * ASI + 256 + c4 * 4) = s;
    }
    b1s[tid] = b1[tid];
    if (tid < 128) b2s[tid] = b2[tid];
    if (tid < 64)  sumsq[tid] = 0.0f;
    __syncthreads();
    tower_core<4, 12, ASI, true>(U, b1s, b2s, sumsq, w1f, w2f, item_bf, row0, nval, tid);
}

__global__ __launch_bounds__(512, 4) void user_kernel(
    const float* __restrict__ gcnu, const int* __restrict__ hist,
    const unsigned short* __restrict__ item_bf,
    const bf8* __restrict__ w1f, const float* __restrict__ b1,
    const bf8* __restrict__ w2f, const float* __restrict__ b2,
    float* __restrict__ outp)
{
    __shared__ __align__(16) unsigned short U[32 * 520];   // union A/H (33.3 KB)
    __shared__ float b1s[512], b2s[128], sumsq[32];
    const int tid = threadIdx.x;
    const int u0 = blockIdx.x * 32;                        // 512 * 32 = 16384 exact
    int* hist_s = (int*)(U + 32 * ASU);                    // 6.4 KB in U tail
    const f4v* g4 = (const f4v*)gcnu;
    #pragma unroll
    for (int j = 0; j < 2; ++j) {             // gcn_user: 32 x 128 -> cols 0..127
        int idx = tid + j * 512; int r = idx >> 5, c4 = idx & 31;
        f4v x = __builtin_nontemporal_load(g4 + (size_t)(u0 + r) * 32 + c4);
        ushort4 s; s.x = f2bf(x[0]); s.y = f2bf(x[1]); s.z = f2bf(x[2]); s.w = f2bf(x[3]);
        *(ushort4*)(U + r * ASU + c4 * 4) = s;
    }
    for (int k = tid; k < 32 * HIST; k += 512)             // stage hist ids once
        hist_s[k] = __builtin_nontemporal_load(hist + (size_t)u0 * HIST + k);
    b1s[tid] = b1[tid];
    if (tid < 128) b2s[tid] = b2[tid];
    if (tid < 32)  sumsq[tid] = 0.0f;
    __syncthreads();
    // gather + mean -> cols 128..255. 16 threads/user, 16 B (8 elems) each.
    // item_bf loads stay CACHED: 210 MB total from a 25.6 MB table (8x reuse).
    {
        const int u = tid >> 4, g = tid & 15;
        float f[8];
        #pragma unroll
        for (int k = 0; k < 8; ++k) f[k] = 0.0f;
        const int* hrow = hist_s + u * HIST;
        #pragma unroll 10
        for (int t = 0; t < HIST; ++t) {
            int id = hrow[t];
            uint4 x = *(const uint4*)(item_bf + (size_t)id * 128 + g * 8);
            unsigned vs[4] = {x.x, x.y, x.z, x.w};
            #pragma unroll
            for (int k = 0; k < 4; ++k) {
                f[2 * k]     += bf2f(vs[k] & 0xffffu);
                f[2 * k + 1] += bf2f(vs[k] >> 16);
            }
        }
        unsigned o[4];
        #pragma unroll
        for (int k = 0; k < 4; ++k)
            o[k] = (unsigned)f2bf(f[2 * k] * 0.02f) | ((unsigned)f2bf(f[2 * k + 1] * 0.02f) << 16);
        uint4 s; s.x = o[0]; s.y = o[1]; s.z = o[2]; s.w = o[3];
        *(uint4*)(U + u * ASU + 128 + g * 8) = s;
    }
    __syncthreads();
    tower_core<2, 8, ASU, false>(U, b1s, b2s, sumsq, w1f, w2f, outp, u0, 32, tid);
}

extern "C" void kernel_launch(void* const* d_in, const int* in_sizes, int n_in,
                              void* d_out, int out_size, void* d_ws, size_t ws_size,
                              hipStream_t stream) {
    const float* text = (const float*)d_in[0];   // [100000,256]
    const float* gcni = (const float*)d_in[1];   // [100000,128]
    const float* gcnu = (const float*)d_in[2];   // [16384,128]
    const int*   hist = (const int*)d_in[3];     // [16384,50]
    const float* W1i  = (const float*)d_in[4];   // [384,512]
    const float* b1i  = (const float*)d_in[5];
    const float* W2i  = (const float*)d_in[6];   // [512,128]
    const float* b2i  = (const float*)d_in[7];
    const float* W1u  = (const float*)d_in[8];   // [256,512]
    const float* b1u  = (const float*)d_in[9];
    const float* W2u  = (const float*)d_in[10];  // [512,128]
    const float* b2u  = (const float*)d_in[11];
    float* out = (float*)d_out;                  // [16384,128] fp32

    unsigned short* itemb = (unsigned short*)d_ws;   // 25.6 MB bf16 item_emb
    unsigned short* pw = itemb + 12800000;           // packed weights (0.9 MB)

    pack_weights<<<224, 256, 0, stream>>>(W1i, W2i, W1u, W2u, pw);
    item_kernel<<<(N_ITEMS + 63) / 64, 512, 0, stream>>>(
        text, gcni, (const bf8*)pw, b1i, (const bf8*)(pw + 196608), b2i, itemb);
    user_kernel<<<N_USERS / 32, 512, 0, stream>>>(
        gcnu, hist, itemb, (const bf8*)(pw + 262144), b1u, (const bf8*)(pw + 393216), b2u, out);
}

// Round 4
// 305.680 us; speedup vs baseline: 1.0697x; 1.0697x over previous
//
#include <hip/hip_runtime.h>
#include <hip/hip_bf16.h>

#define HIST 50
#define N_ITEMS 100000
#define N_USERS 16384

typedef __bf16 bf8 __attribute__((ext_vector_type(8)));
typedef float  f4  __attribute__((ext_vector_type(4)));

__device__ __forceinline__ unsigned short f2bf(float x) {
    unsigned u = __builtin_bit_cast(unsigned, x);
    u += 0x7fffu + ((u >> 16) & 1u);          // RNE
    return (unsigned short)(u >> 16);
}
__device__ __forceinline__ float bf2f(unsigned b) {
    unsigned u = b << 16;
    return __builtin_bit_cast(float, u);
}

// ---------------------------------------------------------------------------
// Weight packer: fp32 [K][N] -> bf16 MFMA B-fragments. (verified r2-r4)
// Frag unit (nt, ks, lane l): 8 bf16 = B[ks*32 + (l>>4)*8 + j][nt*16 + (l&15)]
// stored at frag index (nt*KS + ks)*64 + l (16 B per lane).
// ---------------------------------------------------------------------------
__global__ void pack_weights(const float* __restrict__ W1i, const float* __restrict__ W2i,
                             const float* __restrict__ W1u, const float* __restrict__ W2u,
                             unsigned short* __restrict__ dstbase)
{
    int i = blockIdx.x * 256 + threadIdx.x;   // 57344 total
    const float* W; unsigned short* dst; int N, KS, loc;
    if (i < 24576)      { W = W1i; dst = dstbase;          N = 512; KS = 12; loc = i; }
    else if (i < 32768) { W = W2i; dst = dstbase + 196608; N = 128; KS = 16; loc = i - 24576; }
    else if (i < 49152) { W = W1u; dst = dstbase + 262144; N = 512; KS = 8;  loc = i - 32768; }
    else                { W = W2u; dst = dstbase + 393216; N = 128; KS = 16; loc = i - 49152; }
    int l = loc & 63, fi = loc >> 6;
    int ks = fi % KS, nt = fi / KS;
    int q = l >> 4, c = l & 15;
    const float* src = W + (size_t)(ks * 32 + q * 8) * N + nt * 16 + c;
    unsigned o[4];
    #pragma unroll
    for (int k = 0; k < 4; ++k) {
        unsigned lo = f2bf(src[(2 * k) * N]);
        unsigned hi = f2bf(src[(2 * k + 1) * N]);
        o[k] = lo | (hi << 16);
    }
    uint4 v; v.x = o[0]; v.y = o[1]; v.z = o[2]; v.w = o[3];
    ((uint4*)dst)[(size_t)(nt * KS + ks) * 64 + l] = v;
}

// ---------------------------------------------------------------------------
// Core: NR*16 rows, 8 waves (512 thr). r2 geometry (NR=2) + 1-deep b-frag
// prefetch (clean A/B vs r2's no-prefetch 129.5us: tests whether per-wave
// weight-load latency is the item wall). (512,4): ~4 waves/SIMD.
// Layer1: wave w owns cols [w*64, w*64+64) (4 nt); acc1[NR][4].
// Layer2: rg=w>>2 row group, jj=w&3 col quarter; acc2[NR/2][2].
// MFMA 16x16x32 bf16: A-frag m=l&15,k=q*8+j; B n=l&15,k same; D row=q*4+reg,
// col=l&15 (m89-verified).
// ---------------------------------------------------------------------------
template<int NR, int KS1, int ASTR, bool OUT_BF16>
__device__ __forceinline__ void tower_core(
    unsigned short* U, const float* b1s, const float* b2s, float* sumsq,
    const bf8* __restrict__ w1f, const bf8* __restrict__ w2f,
    void* __restrict__ outp, int row0, int tid)
{
    const int HSTR = 520;                     // 1040 B = 65*16: even bank spread
    const int l = tid & 63, w = tid >> 6;     // w in 0..7
    const int q = l >> 4, c = l & 15;

    f4 acc1[NR][4];
    #pragma unroll
    for (int i = 0; i < NR; ++i)
        #pragma unroll
        for (int j = 0; j < 4; ++j) acc1[i][j] = (f4)0.0f;

    const unsigned short* ap = U + c * ASTR + q * 8;
    bf8 bcur[4], bnxt[4];
    #pragma unroll
    for (int nt = 0; nt < 4; ++nt)
        bcur[nt] = w1f[(size_t)((w * 4 + nt) * KS1 + 0) * 64 + l];
    #pragma unroll
    for (int ks = 0; ks < KS1; ++ks) {
        if (ks + 1 < KS1) {
            #pragma unroll
            for (int nt = 0; nt < 4; ++nt)
                bnxt[nt] = w1f[(size_t)((w * 4 + nt) * KS1 + ks + 1) * 64 + l];
        }
        bf8 a[NR];
        #pragma unroll
        for (int rt = 0; rt < NR; ++rt)
            a[rt] = *(const bf8*)(ap + rt * 16 * ASTR + ks * 32);
        #pragma unroll
        for (int rt = 0; rt < NR; ++rt)
            #pragma unroll
            for (int nt = 0; nt < 4; ++nt)
                acc1[rt][nt] = __builtin_amdgcn_mfma_f32_16x16x32_bf16(a[rt], bcur[nt], acc1[rt][nt], 0, 0, 0);
        #pragma unroll
        for (int nt = 0; nt < 4; ++nt) bcur[nt] = bnxt[nt];
    }
    __syncthreads();                          // all A reads done; U becomes H

    #pragma unroll
    for (int nt = 0; nt < 4; ++nt) {
        int col = w * 64 + nt * 16 + c;
        float bias = b1s[col];
        #pragma unroll
        for (int rt = 0; rt < NR; ++rt)
            #pragma unroll
            for (int reg = 0; reg < 4; ++reg) {
                float h = fmaxf(acc1[rt][nt][reg] + bias, 0.0f);
                U[(rt * 16 + q * 4 + reg) * HSTR + col] = f2bf(h);
            }
    }
    __syncthreads();

    // layer 2: K=512 (16 k-steps); wave w: rows rg*(NR2*16).., cols jj*32..+31
    constexpr int NR2 = NR / 2;
    const int rg = w >> 2, jj = w & 3;
    f4 acc2[NR2][2];
    #pragma unroll
    for (int i = 0; i < NR2; ++i) { acc2[i][0] = (f4)0.0f; acc2[i][1] = (f4)0.0f; }

    const unsigned short* hp = U + (size_t)(rg * NR2 * 16 + c) * HSTR + q * 8;
    bf8 ccur[2], cnxt[2];
    ccur[0] = w2f[(size_t)((jj * 2 + 0) * 16 + 0) * 64 + l];
    ccur[1] = w2f[(size_t)((jj * 2 + 1) * 16 + 0) * 64 + l];
    #pragma unroll
    for (int ks = 0; ks < 16; ++ks) {
        if (ks + 1 < 16) {
            cnxt[0] = w2f[(size_t)((jj * 2 + 0) * 16 + ks + 1) * 64 + l];
            cnxt[1] = w2f[(size_t)((jj * 2 + 1) * 16 + ks + 1) * 64 + l];
        }
        bf8 a[NR2];
        #pragma unroll
        for (int i = 0; i < NR2; ++i)
            a[i] = *(const bf8*)(hp + i * 16 * HSTR + ks * 32);
        #pragma unroll
        for (int i = 0; i < NR2; ++i) {
            acc2[i][0] = __builtin_amdgcn_mfma_f32_16x16x32_bf16(a[i], ccur[0], acc2[i][0], 0, 0, 0);
            acc2[i][1] = __builtin_amdgcn_mfma_f32_16x16x32_bf16(a[i], ccur[1], acc2[i][1], 0, 0, 0);
        }
        ccur[0] = cnxt[0]; ccur[1] = cnxt[1];
    }

    // epilogue: +b2, l2norm (16-lane shfl + LDS atomic across jj-waves), store
    float v[NR2][2][4];
    #pragma unroll
    for (int i = 0; i < NR2; ++i)
        #pragma unroll
        for (int j = 0; j < 2; ++j) {
            float bias = b2s[jj * 32 + j * 16 + c];
            #pragma unroll
            for (int reg = 0; reg < 4; ++reg)
                v[i][j][reg] = acc2[i][j][reg] + bias;
        }
    #pragma unroll
    for (int i = 0; i < NR2; ++i)
        #pragma unroll
        for (int reg = 0; reg < 4; ++reg) {
            float s = v[i][0][reg] * v[i][0][reg] + v[i][1][reg] * v[i][1][reg];
            s += __shfl_xor(s, 1); s += __shfl_xor(s, 2);
            s += __shfl_xor(s, 4); s += __shfl_xor(s, 8);
            if (c == 0) atomicAdd(&sumsq[rg * NR2 * 16 + i * 16 + q * 4 + reg], s);
        }
    __syncthreads();
    #pragma unroll
    for (int i = 0; i < NR2; ++i)
        #pragma unroll
        for (int reg = 0; reg < 4; ++reg) {
            int row = rg * NR2 * 16 + i * 16 + q * 4 + reg;
            float inv = 1.0f / fmaxf(sqrtf(sumsq[row]), 1e-12f);
            #pragma unroll
            for (int j = 0; j < 2; ++j) {
                int col = jj * 32 + j * 16 + c;
                float o = v[i][j][reg] * inv;
                if (OUT_BF16)
                    ((unsigned short*)outp)[(size_t)(row0 + row) * 128 + col] = f2bf(o);
                else
                    ((float*)outp)[(size_t)(row0 + row) * 128 + col] = o;
            }
        }
}

#define ASI 392   // item A stride (384+8): 784 B = 49*16 -> even bank spread
#define ASU 264   // user A stride (256+8): 528 B = 33*16

__global__ __launch_bounds__(512, 4) void item_kernel(
    const float* __restrict__ text, const float* __restrict__ gcn,
    const bf8* __restrict__ w1f, const float* __restrict__ b1,
    const bf8* __restrict__ w2f, const float* __restrict__ b2,
    unsigned short* __restrict__ item_bf)
{
    __shared__ __align__(16) unsigned short U[32 * 520];   // 33.3 KB union A/H
    __shared__ float b1s[512], b2s[128], sumsq[32];
    const int tid = threadIdx.x;
    const int row0 = blockIdx.x * 32;                      // 3125 * 32 = 100000 exact
    const float4* t4 = (const float4*)text;
    const float4* g4 = (const float4*)gcn;
    #pragma unroll
    for (int j = 0; j < 4; ++j) {             // text: 32 x 256 (2048 float4)
        int idx = tid + j * 512; int r = idx >> 6, c4 = idx & 63;
        float4 x = t4[(size_t)(row0 + r) * 64 + c4];
        ushort4 s; s.x = f2bf(x.x); s.y = f2bf(x.y); s.z = f2bf(x.z); s.w = f2bf(x.w);
        *(ushort4*)(U + r * ASI + c4 * 4) = s;
    }
    #pragma unroll
    for (int j = 0; j < 2; ++j) {             // gcn: 32 x 128 (1024 float4)
        int idx = tid + j * 512; int r = idx >> 5, c4 = idx & 31;
        float4 x = g4[(size_t)(row0 + r) * 32 + c4];
        ushort4 s; s.x = f2bf(x.x); s.y = f2bf(x.y); s.z = f2bf(x.z); s.w = f2bf(x.w);
        *(ushort4*)(U + r * ASI + 256 + c4 * 4) = s;
    }
    b1s[tid] = b1[tid];
    if (tid < 128) b2s[tid] = b2[tid];
    if (tid < 32)  sumsq[tid] = 0.0f;
    __syncthreads();
    tower_core<2, 12, ASI, true>(U, b1s, b2s, sumsq, w1f, w2f, item_bf, row0, tid);
}

__global__ __launch_bounds__(512, 4) void user_kernel(
    const float* __restrict__ gcnu, const int* __restrict__ hist,
    const unsigned short* __restrict__ item_bf,
    const bf8* __restrict__ w1f, const float* __restrict__ b1,
    const bf8* __restrict__ w2f, const float* __restrict__ b2,
    float* __restrict__ outp)
{
    __shared__ __align__(16) unsigned short U[32 * 520];   // union A/H (33.3 KB)
    __shared__ float b1s[512], b2s[128], sumsq[32];
    const int tid = threadIdx.x;
    const int u0 = blockIdx.x * 32;                        // 512 * 32 = 16384 exact
    int* hist_s = (int*)(U + 32 * ASU);                    // 6.4 KB in U tail
    const float4* g4 = (const float4*)gcnu;
    #pragma unroll
    for (int j = 0; j < 2; ++j) {             // gcn_user: 32 x 128 -> cols 0..127
        int idx = tid + j * 512; int r = idx >> 5, c4 = idx & 31;
        float4 x = g4[(size_t)(u0 + r) * 32 + c4];
        ushort4 s; s.x = f2bf(x.x); s.y = f2bf(x.y); s.z = f2bf(x.z); s.w = f2bf(x.w);
        *(ushort4*)(U + r * ASU + c4 * 4) = s;
    }
    for (int k = tid; k < 32 * HIST; k += 512)             // stage hist ids once
        hist_s[k] = hist[(size_t)u0 * HIST + k];
    b1s[tid] = b1[tid];
    if (tid < 128) b2s[tid] = b2[tid];
    if (tid < 32)  sumsq[tid] = 0.0f;
    __syncthreads();
    // gather + mean -> cols 128..255. 16 threads/user, 16 B (8 elems) each.
    // Ids preloaded to registers (static indexing), gather FULLY unrolled so
    // all 50 load addresses are known upfront -> deep MLP instead of ~10.
    {
        const int u = tid >> 4, g = tid & 15;
        int ids[HIST];
        #pragma unroll
        for (int t = 0; t < HIST; ++t) ids[t] = hist_s[u * HIST + t];
        float f[8];
        #pragma unroll
        for (int k = 0; k < 8; ++k) f[k] = 0.0f;
        #pragma unroll
        for (int t = 0; t < HIST; ++t) {
            uint4 x = *(const uint4*)(item_bf + (size_t)ids[t] * 128 + g * 8);
            unsigned vs[4] = {x.x, x.y, x.z, x.w};
            #pragma unroll
            for (int k = 0; k < 4; ++k) {
                f[2 * k]     += bf2f(vs[k] & 0xffffu);
                f[2 * k + 1] += bf2f(vs[k] >> 16);
            }
        }
        unsigned o[4];
        #pragma unroll
        for (int k = 0; k < 4; ++k)
            o[k] = (unsigned)f2bf(f[2 * k] * 0.02f) | ((unsigned)f2bf(f[2 * k + 1] * 0.02f) << 16);
        uint4 s; s.x = o[0]; s.y = o[1]; s.z = o[2]; s.w = o[3];
        *(uint4*)(U + u * ASU + 128 + g * 8) = s;
    }
    __syncthreads();
    tower_core<2, 8, ASU, false>(U, b1s, b2s, sumsq, w1f, w2f, outp, u0, tid);
}

extern "C" void kernel_launch(void* const* d_in, const int* in_sizes, int n_in,
                              void* d_out, int out_size, void* d_ws, size_t ws_size,
                              hipStream_t stream) {
    const float* text = (const float*)d_in[0];   // [100000,256]
    const float* gcni = (const float*)d_in[1];   // [100000,128]
    const float* gcnu = (const float*)d_in[2];   // [16384,128]
    const int*   hist = (const int*)d_in[3];     // [16384,50]
    const float* W1i  = (const float*)d_in[4];   // [384,512]
    const float* b1i  = (const float*)d_in[5];
    const float* W2i  = (const float*)d_in[6];   // [512,128]
    const float* b2i  = (const float*)d_in[7];
    const float* W1u  = (const float*)d_in[8];   // [256,512]
    const float* b1u  = (const float*)d_in[9];
    const float* W2u  = (const float*)d_in[10];  // [512,128]
    const float* b2u  = (const float*)d_in[11];
    float* out = (float*)d_out;                  // [16384,128] fp32

    unsigned short* itemb = (unsigned short*)d_ws;   // 25.6 MB bf16 item_emb
    unsigned short* pw = itemb + 12800000;           // packed weights (0.9 MB)

    pack_weights<<<224, 256, 0, stream>>>(W1i, W2i, W1u, W2u, pw);
    item_kernel<<<N_ITEMS / 32, 512, 0, stream>>>(
        text, gcni, (const bf8*)pw, b1i, (const bf8*)(pw + 196608), b2i, itemb);
    user_kernel<<<N_USERS / 32, 512, 0, stream>>>(
        gcnu, hist, itemb, (const bf8*)(pw + 262144), b1u, (const bf8*)(pw + 393216), b2u, out);
}